// Round 2
// baseline (59419.293 us; speedup 1.0000x reference)
//
#include <hip/hip_runtime.h>
#include <hip/hip_bf16.h>

#define B_ 16
#define S_ 256
#define E_ 512
#define H_ 1024
#define V_ 32000
#define NB_ 256   // scan grid size == barrier participants

typedef __attribute__((ext_vector_type(8))) short short8;
typedef __attribute__((ext_vector_type(4))) float f32x4;

__device__ __forceinline__ unsigned short f2bf(float f) {
  unsigned u = __builtin_bit_cast(unsigned, f);
  u = u + 0x7fffu + ((u >> 16) & 1u);   // round-to-nearest-even
  return (unsigned short)(u >> 16);
}

// ---------------- prep kernels ----------------

__global__ void k_init(float* __restrict__ p, int n) {
  int i = blockIdx.x * 256 + threadIdx.x;
  if (i < n) p[i] = 0.f;
}

__global__ void k_cast(const float* __restrict__ s, unsigned short* __restrict__ d, int n4) {
  int i = blockIdx.x * 256 + threadIdx.x;
  if (i >= n4) return;
  float4 v = ((const float4*)s)[i];
  ushort4 o;
  o.x = f2bf(v.x); o.y = f2bf(v.y); o.z = f2bf(v.z); o.w = f2bf(v.w);
  ((ushort4*)d)[i] = o;
}

// xe[m][k] = bf16(emb[x[b,s]][k]), m = s*16 + b
__global__ void k_gather(const int* __restrict__ x, const float* __restrict__ emb,
                         unsigned short* __restrict__ xe) {
  int m = blockIdx.x;
  int s = m >> 4, b = m & 15;
  int tok = x[b * S_ + s];
  int k = threadIdx.x * 4;
  float4 v = *(const float4*)(emb + (size_t)tok * E_ + k);
  ushort4 o;
  o.x = f2bf(v.x); o.y = f2bf(v.y); o.z = f2bf(v.z); o.w = f2bf(v.w);
  *(ushort4*)(xe + (size_t)m * E_ + k) = o;
}

// ---------------- bf16 MFMA GEMM:  C[m][n] = sum_k A[m,k]*W[n,k] + bias[n] ----------------

__global__ __launch_bounds__(256, 1) void k_gemm(
    const unsigned short* __restrict__ A,
    const unsigned short* __restrict__ W0, const unsigned short* __restrict__ W1,
    const unsigned short* __restrict__ W2,
    const float* __restrict__ b0, const float* __restrict__ b1, const float* __restrict__ b2,
    float* __restrict__ C, int K, int mtiles, int gshift, int permute, int ldc) {
  __shared__ unsigned short As[128][40];
  __shared__ unsigned short Bs[128][40];

  const int tid = threadIdx.x;
  const int mt = blockIdx.x % mtiles, nt = blockIdx.x / mtiles;
  const int m0 = mt * 128, n0 = nt * 128;
  const int wave = tid >> 6, lane = tid & 63;
  const int wm = (wave >> 1) * 64, wn = (wave & 1) * 64;
  const int lr = lane & 15, lk = (lane >> 4) * 8;
  const int ar = tid >> 2, as = (tid & 3) * 8;
  const unsigned kmask = (1u << gshift) - 1u;

  int j1 = n0 + ar, j2 = n0 + ar + 64;
  int g1 = j1 >> gshift, g2 = j2 >> gshift;
  const unsigned short* bp1 = (g1 == 0 ? W0 : (g1 == 1 ? W1 : W2)) + (size_t)(j1 & kmask) * K + as;
  const unsigned short* bp2 = (g2 == 0 ? W0 : (g2 == 1 ? W1 : W2)) + (size_t)(j2 & kmask) * K + as;
  const unsigned short* ap1 = A + (size_t)(m0 + ar) * K + as;
  const unsigned short* ap2 = A + (size_t)(m0 + ar + 64) * K + as;

  const f32x4 zero4 = {0.f, 0.f, 0.f, 0.f};
  f32x4 acc[4][4];
#pragma unroll
  for (int i = 0; i < 4; ++i)
#pragma unroll
    for (int j = 0; j < 4; ++j) acc[i][j] = zero4;

  for (int k0 = 0; k0 < K; k0 += 32) {
    int4 va1 = *(const int4*)(ap1 + k0);
    int4 va2 = *(const int4*)(ap2 + k0);
    int4 vb1 = *(const int4*)(bp1 + k0);
    int4 vb2 = *(const int4*)(bp2 + k0);
    __syncthreads();
    *(int4*)&As[ar][as] = va1;
    *(int4*)&As[ar + 64][as] = va2;
    *(int4*)&Bs[ar][as] = vb1;
    *(int4*)&Bs[ar + 64][as] = vb2;
    __syncthreads();
    short8 af[4], bf[4];
#pragma unroll
    for (int i = 0; i < 4; ++i) af[i] = *(const short8*)&As[wm + i * 16 + lr][lk];
#pragma unroll
    for (int j = 0; j < 4; ++j) bf[j] = *(const short8*)&Bs[wn + j * 16 + lr][lk];
#pragma unroll
    for (int i = 0; i < 4; ++i)
#pragma unroll
      for (int j = 0; j < 4; ++j)
        acc[i][j] = __builtin_amdgcn_mfma_f32_16x16x32_bf16(af[i], bf[j], acc[i][j], 0, 0, 0);
  }

#pragma unroll
  for (int j = 0; j < 4; ++j) {
    int col = n0 + wn + j * 16 + lr;
    int g = col >> gshift;
    const float* bp = (g == 0 ? b0 : (g == 1 ? b1 : b2));
    float bv = bp[col & kmask];
#pragma unroll
    for (int i = 0; i < 4; ++i) {
      int rbase = m0 + wm + i * 16 + (lane >> 4) * 4;
#pragma unroll
      for (int r = 0; r < 4; ++r) {
        int mrow = rbase + r;
        size_t off;
        if (permute) {
          int s = mrow >> 4, b = mrow & 15;
          off = ((size_t)(b * S_ + s)) * ldc + col;
        } else {
          off = (size_t)mrow * ldc + col;
        }
        C[off] = acc[i][j][r] + bv;
      }
    }
  }
}

// ---------------- fast epoch grid barrier (distributed flags) ----------------
// bar layout: arrive flags at bar[i*32] (128B apart, one per block), release at bar[NB_*32].
__device__ __forceinline__ void gbar(unsigned* __restrict__ bar, unsigned ep) {
  __syncthreads();
  if (threadIdx.x == 0) {
    __threadfence();  // make this block's phase writes agent-visible
    __hip_atomic_store(bar + (unsigned)blockIdx.x * 32, ep, __ATOMIC_RELEASE,
                       __HIP_MEMORY_SCOPE_AGENT);
  }
  if (blockIdx.x == 0) {
    // 256 threads each poll one block's flag (distinct cachelines, parallel)
    while (__hip_atomic_load(bar + (unsigned)threadIdx.x * 32, __ATOMIC_ACQUIRE,
                             __HIP_MEMORY_SCOPE_AGENT) < ep)
      __builtin_amdgcn_s_sleep(1);
    __threadfence();
    __syncthreads();
    if (threadIdx.x == 0)
      __hip_atomic_store(bar + NB_ * 32, ep, __ATOMIC_RELEASE, __HIP_MEMORY_SCOPE_AGENT);
  } else {
    if (threadIdx.x == 0) {
      while (__hip_atomic_load(bar + NB_ * 32, __ATOMIC_ACQUIRE,
                               __HIP_MEMORY_SCOPE_AGENT) < ep)
        __builtin_amdgcn_s_sleep(1);
      __threadfence();
    }
    __syncthreads();
  }
}

// ---------------- persistent GRU scan ----------------
// 256 blocks x 256 threads. Wave w of block blk owns feature j = blk*4 + w
// (all 3 gate rows: 48 f32/lane — fits registers, no spill) and computes it
// for all 16 batches. Lane owns k-chunk kb = lane*16.
__global__ __launch_bounds__(256, 1) void k_scan(
    const float* __restrict__ Gx,  // [S][B][3H]  (z|r|n)
    const float* __restrict__ Whz, const float* __restrict__ Whr, const float* __restrict__ Whn,
    float* __restrict__ h,         // [B][H] f32 state
    float* __restrict__ rh,        // [B][H] scratch: r*h
    unsigned short* __restrict__ Hseq,  // [S][B][H] bf16
    float* __restrict__ hfin,      // [B][H] f32 (d_out tail)
    unsigned* __restrict__ bar) {
  const int tid = threadIdx.x;
  const int wave = tid >> 6, lane = tid & 63;
  const int j = blockIdx.x * 4 + wave;  // this wave's feature
  const int kb = lane * 16;

  float4 wz[4], wr[4], wn[4];
  {
    const float4* pz = (const float4*)(Whz + (size_t)j * H_ + kb);
    const float4* pr = (const float4*)(Whr + (size_t)j * H_ + kb);
    const float4* pn = (const float4*)(Whn + (size_t)j * H_ + kb);
#pragma unroll
    for (int i = 0; i < 4; ++i) { wz[i] = pz[i]; wr[i] = pr[i]; wn[i] = pn[i]; }
  }

  float zarr[B_];
  unsigned ep = 0;

  for (int t = 0; t < S_; ++t) {
    const float* gxt = Gx + (size_t)t * (B_ * 3 * H_);

    // -------- phase A: z, r, rh --------
#pragma unroll 4
    for (int b = 0; b < B_; ++b) {
      const float4* hp = (const float4*)(h + b * H_ + kb);
      float az = 0.f, ar = 0.f;
#pragma unroll
      for (int i = 0; i < 4; ++i) {
        float4 h4 = hp[i];
        az += wz[i].x * h4.x + wz[i].y * h4.y + wz[i].z * h4.z + wz[i].w * h4.w;
        ar += wr[i].x * h4.x + wr[i].y * h4.y + wr[i].z * h4.z + wr[i].w * h4.w;
      }
#pragma unroll
      for (int off = 32; off; off >>= 1) {
        az += __shfl_xor(az, off);
        ar += __shfl_xor(ar, off);
      }
      float gz = gxt[b * 3 * H_ + j];
      float gr = gxt[b * 3 * H_ + H_ + j];
      zarr[b] = 1.f / (1.f + __expf(-(gz + az)));
      float r = 1.f / (1.f + __expf(-(gr + ar)));
      if (lane == 0) rh[b * H_ + j] = r * h[b * H_ + j];
    }
    gbar(bar, ++ep);

    // -------- phase B: n, h update --------
#pragma unroll 4
    for (int b = 0; b < B_; ++b) {
      const float4* rp = (const float4*)(rh + b * H_ + kb);
      float an = 0.f;
#pragma unroll
      for (int i = 0; i < 4; ++i) {
        float4 r4 = rp[i];
        an += wn[i].x * r4.x + wn[i].y * r4.y + wn[i].z * r4.z + wn[i].w * r4.w;
      }
#pragma unroll
      for (int off = 32; off; off >>= 1) an += __shfl_xor(an, off);
      if (lane == 0) {
        float gn = gxt[b * 3 * H_ + 2 * H_ + j];
        float n = tanhf(gn + an);
        float z = zarr[b];
        float ho = h[b * H_ + j];
        float hn = (1.f - z) * n + z * ho;
        h[b * H_ + j] = hn;
        Hseq[(size_t)t * (B_ * H_) + b * H_ + j] = f2bf(hn);
        if (t == S_ - 1) hfin[b * H_ + j] = hn;
      }
    }
    gbar(bar, ++ep);
  }
}

// ---------------- host ----------------

extern "C" void kernel_launch(void* const* d_in, const int* in_sizes, int n_in,
                              void* d_out, int out_size, void* d_ws, size_t ws_size,
                              hipStream_t stream) {
  const int*   x    = (const int*)d_in[0];
  const float* emb  = (const float*)d_in[1];
  const float* wxz0 = (const float*)d_in[2];
  const float* bxz0 = (const float*)d_in[3];
  const float* whz0 = (const float*)d_in[4];
  const float* wxr0 = (const float*)d_in[5];
  const float* bxr0 = (const float*)d_in[6];
  const float* whr0 = (const float*)d_in[7];
  const float* wxn0 = (const float*)d_in[8];
  const float* bxn0 = (const float*)d_in[9];
  const float* whn0 = (const float*)d_in[10];
  const float* wxz1 = (const float*)d_in[11];
  const float* bxz1 = (const float*)d_in[12];
  const float* whz1 = (const float*)d_in[13];
  const float* wxr1 = (const float*)d_in[14];
  const float* bxr1 = (const float*)d_in[15];
  const float* whr1 = (const float*)d_in[16];
  const float* wxn1 = (const float*)d_in[17];
  const float* bxn1 = (const float*)d_in[18];
  const float* whn1 = (const float*)d_in[19];
  const float* fcw  = (const float*)d_in[20];
  const float* fcb  = (const float*)d_in[21];
  float* out = (float*)d_out;

  char* w = (char*)d_ws;
  size_t off = 0;
  auto alloc = [&](size_t bytes) {
    void* p = w + off;
    off += (bytes + 255) & ~(size_t)255;
    return p;
  };
  unsigned short* xe   = (unsigned short*)alloc((size_t)4096 * E_ * 2);
  unsigned short* wz0b = (unsigned short*)alloc((size_t)H_ * E_ * 2);
  unsigned short* wr0b = (unsigned short*)alloc((size_t)H_ * E_ * 2);
  unsigned short* wn0b = (unsigned short*)alloc((size_t)H_ * E_ * 2);
  unsigned short* wz1b = (unsigned short*)alloc((size_t)H_ * H_ * 2);
  unsigned short* wr1b = (unsigned short*)alloc((size_t)H_ * H_ * 2);
  unsigned short* wn1b = (unsigned short*)alloc((size_t)H_ * H_ * 2);
  unsigned short* fcwb = (unsigned short*)alloc((size_t)V_ * H_ * 2);
  float* Gx = (float*)alloc((size_t)4096 * 3 * H_ * 4);
  unsigned short* Hs0 = (unsigned short*)alloc((size_t)4096 * H_ * 2);
  unsigned short* Hs1 = (unsigned short*)alloc((size_t)4096 * H_ * 2);
  // zero-init region (contiguous, all sizes multiples of 256B):
  float* h0c = (float*)alloc((size_t)B_ * H_ * 4);
  float* h1c = (float*)alloc((size_t)B_ * H_ * 4);
  float* rh  = (float*)alloc((size_t)B_ * H_ * 4);
  unsigned* bar0 = (unsigned*)alloc((size_t)(NB_ * 32 + 64) * 4);  // 128B-spaced flags + release
  unsigned* bar1 = (unsigned*)alloc((size_t)(NB_ * 32 + 64) * 4);
  size_t zero_end = off;

  float* h0f = out + (size_t)B_ * S_ * V_;
  float* h1f = h0f + (size_t)B_ * H_;

  // zero h0c..bar1 (contiguous)
  {
    size_t zbytes = zero_end - ((char*)h0c - w);
    int nz = (int)(zbytes / 4);
    k_init<<<(nz + 255) / 256, 256, 0, stream>>>(h0c, nz);
  }

  // prep: gather + casts
  k_gather<<<4096, 128, 0, stream>>>(x, emb, xe);
  k_cast<<<(H_ * E_ / 4 + 255) / 256, 256, 0, stream>>>(wxz0, wz0b, H_ * E_ / 4);
  k_cast<<<(H_ * E_ / 4 + 255) / 256, 256, 0, stream>>>(wxr0, wr0b, H_ * E_ / 4);
  k_cast<<<(H_ * E_ / 4 + 255) / 256, 256, 0, stream>>>(wxn0, wn0b, H_ * E_ / 4);
  k_cast<<<(H_ * H_ / 4 + 255) / 256, 256, 0, stream>>>(wxz1, wz1b, H_ * H_ / 4);
  k_cast<<<(H_ * H_ / 4 + 255) / 256, 256, 0, stream>>>(wxr1, wr1b, H_ * H_ / 4);
  k_cast<<<(H_ * H_ / 4 + 255) / 256, 256, 0, stream>>>(wxn1, wn1b, H_ * H_ / 4);
  k_cast<<<(V_ * H_ / 4 + 255) / 256, 256, 0, stream>>>(fcw, fcwb, V_ * H_ / 4);

  // Gx0 = xe @ Wx0^T + b  (M=4096, N=3072, K=512)
  k_gemm<<<32 * 24, 256, 0, stream>>>(xe, wz0b, wr0b, wn0b, bxz0, bxr0, bxn0,
                                      Gx, E_, 32, 10, 0, 3 * H_);
  // layer-0 scan
  k_scan<<<NB_, 256, 0, stream>>>(Gx, whz0, whr0, whn0, h0c, rh, Hs0, h0f, bar0);
  // Gx1 = H0seq @ Wx1^T + b  (K=1024)
  k_gemm<<<32 * 24, 256, 0, stream>>>(Hs0, wz1b, wr1b, wn1b, bxz1, bxr1, bxn1,
                                      Gx, H_, 32, 10, 0, 3 * H_);
  // layer-1 scan
  k_scan<<<NB_, 256, 0, stream>>>(Gx, whz1, whr1, whn1, h1c, rh, Hs1, h1f, bar1);
  // out = H1seq @ fcw^T + fcb  (M=4096, N=32000, K=1024), permuted to [B][S][V]
  k_gemm<<<32 * 250, 256, 0, stream>>>(Hs1, fcwb, fcwb, fcwb, fcb, fcb, fcb,
                                       out, H_, 32, 30, 1, V_);

  (void)in_sizes; (void)n_in; (void)out_size; (void)ws_size;
}

// Round 3
// 6675.009 us; speedup vs baseline: 8.9018x; 8.9018x over previous
//
#include <hip/hip_runtime.h>
#include <hip/hip_bf16.h>

#define B_ 16
#define S_ 256
#define E_ 512
#define H_ 1024
#define V_ 32000
#define SCAN_NB 32   // scan grid = barrier participants

typedef __attribute__((ext_vector_type(8))) short short8;
typedef __attribute__((ext_vector_type(4))) float f32x4;
typedef unsigned long long ull;

union F8 { short8 s8; ull u[2]; };

__device__ __forceinline__ unsigned short f2h(float f) {
  _Float16 h = (_Float16)f;
  return __builtin_bit_cast(unsigned short, h);
}

// ---------------- prep kernels ----------------

__global__ void k_init(unsigned* __restrict__ p, int n) {
  int i = blockIdx.x * 256 + threadIdx.x;
  if (i < n) p[i] = 0u;
}

__global__ void k_cast(const float* __restrict__ s, unsigned short* __restrict__ d, int n4) {
  int i = blockIdx.x * 256 + threadIdx.x;
  if (i >= n4) return;
  float4 v = ((const float4*)s)[i];
  ushort4 o;
  o.x = f2h(v.x); o.y = f2h(v.y); o.z = f2h(v.z); o.w = f2h(v.w);
  ((ushort4*)d)[i] = o;
}

// xe[m][k] = f16(emb[x[b,s]][k]), m = s*16 + b
__global__ void k_gather(const int* __restrict__ x, const float* __restrict__ emb,
                         unsigned short* __restrict__ xe) {
  int m = blockIdx.x;
  int s = m >> 4, b = m & 15;
  int tok = x[b * S_ + s];
  int k = threadIdx.x * 4;
  float4 v = *(const float4*)(emb + (size_t)tok * E_ + k);
  ushort4 o;
  o.x = f2h(v.x); o.y = f2h(v.y); o.z = f2h(v.z); o.w = f2h(v.w);
  *(ushort4*)(xe + (size_t)m * E_ + k) = o;
}

// ---------------- f16 MFMA GEMM:  C[m][n] = sum_k A[m,k]*W[n,k] + bias[n] ----------------

__global__ __launch_bounds__(256, 1) void k_gemm(
    const unsigned short* __restrict__ A,
    const unsigned short* __restrict__ W0, const unsigned short* __restrict__ W1,
    const unsigned short* __restrict__ W2,
    const float* __restrict__ b0, const float* __restrict__ b1, const float* __restrict__ b2,
    float* __restrict__ C, int K, int mtiles, int gshift, int permute, int ldc) {
  __shared__ unsigned short As[128][40];
  __shared__ unsigned short Bs[128][40];

  const int tid = threadIdx.x;
  const int mt = blockIdx.x % mtiles, nt = blockIdx.x / mtiles;
  const int m0 = mt * 128, n0 = nt * 128;
  const int wave = tid >> 6, lane = tid & 63;
  const int wm = (wave >> 1) * 64, wn = (wave & 1) * 64;
  const int lr = lane & 15, lk = (lane >> 4) * 8;
  const int ar = tid >> 2, as = (tid & 3) * 8;
  const unsigned kmask = (1u << gshift) - 1u;

  int j1 = n0 + ar, j2 = n0 + ar + 64;
  int g1 = j1 >> gshift, g2 = j2 >> gshift;
  const unsigned short* bp1 = (g1 == 0 ? W0 : (g1 == 1 ? W1 : W2)) + (size_t)(j1 & kmask) * K + as;
  const unsigned short* bp2 = (g2 == 0 ? W0 : (g2 == 1 ? W1 : W2)) + (size_t)(j2 & kmask) * K + as;
  const unsigned short* ap1 = A + (size_t)(m0 + ar) * K + as;
  const unsigned short* ap2 = A + (size_t)(m0 + ar + 64) * K + as;

  const f32x4 zero4 = {0.f, 0.f, 0.f, 0.f};
  f32x4 acc[4][4];
#pragma unroll
  for (int i = 0; i < 4; ++i)
#pragma unroll
    for (int j = 0; j < 4; ++j) acc[i][j] = zero4;

  for (int k0 = 0; k0 < K; k0 += 32) {
    int4 va1 = *(const int4*)(ap1 + k0);
    int4 va2 = *(const int4*)(ap2 + k0);
    int4 vb1 = *(const int4*)(bp1 + k0);
    int4 vb2 = *(const int4*)(bp2 + k0);
    __syncthreads();
    *(int4*)&As[ar][as] = va1;
    *(int4*)&As[ar + 64][as] = va2;
    *(int4*)&Bs[ar][as] = vb1;
    *(int4*)&Bs[ar + 64][as] = vb2;
    __syncthreads();
    short8 af[4], bf[4];
#pragma unroll
    for (int i = 0; i < 4; ++i) af[i] = *(const short8*)&As[wm + i * 16 + lr][lk];
#pragma unroll
    for (int j = 0; j < 4; ++j) bf[j] = *(const short8*)&Bs[wn + j * 16 + lr][lk];
#pragma unroll
    for (int i = 0; i < 4; ++i)
#pragma unroll
      for (int j = 0; j < 4; ++j)
        acc[i][j] = __builtin_amdgcn_mfma_f32_16x16x32_f16(af[i], bf[j], acc[i][j], 0, 0, 0);
  }

#pragma unroll
  for (int j = 0; j < 4; ++j) {
    int col = n0 + wn + j * 16 + lr;
    int g = col >> gshift;
    const float* bp = (g == 0 ? b0 : (g == 1 ? b1 : b2));
    float bv = bp[col & kmask];
#pragma unroll
    for (int i = 0; i < 4; ++i) {
      int rbase = m0 + wm + i * 16 + (lane >> 4) * 4;
#pragma unroll
      for (int r = 0; r < 4; ++r) {
        int mrow = rbase + r;
        size_t off;
        if (permute) {
          int s = mrow >> 4, b = mrow & 15;
          off = ((size_t)(b * S_ + s)) * ldc + col;
        } else {
          off = (size_t)mrow * ldc + col;
        }
        C[off] = acc[i][j][r] + bv;
      }
    }
  }
}

// ---------------- scan helpers ----------------

// Poll all SCAN_NB per-block flags (relaxed agent loads: NO cache invalidation).
__device__ __forceinline__ void pollf(unsigned* __restrict__ flags, unsigned target) {
  if (threadIdx.x < 64) {
    const int lane = threadIdx.x;
    const bool act = lane < SCAN_NB;
    unsigned* p = flags + (unsigned)lane * 32u;  // 128B-spaced
    while (true) {
      unsigned f = act ? __hip_atomic_load(p, __ATOMIC_RELAXED, __HIP_MEMORY_SCOPE_AGENT)
                       : target;
      if (__all((int)(f >= target))) break;
      __builtin_amdgcn_s_sleep(2);
    }
  }
  __syncthreads();
  asm volatile("" ::: "memory");
}

// Publish 4 f16 values (b=bq+r, j=j0+lj) into comm[b][j]: pair adjacent features
// across lanes so stores are native 4B relaxed-agent atomics (LLC write-through).
__device__ __forceinline__ void pack_store(unsigned short* __restrict__ base,
                                           int j0, int lj, int bq,
                                           unsigned short u0, unsigned short u1,
                                           unsigned short u2, unsigned short u3) {
  int p0 = __shfl_xor((int)u0, 1);
  int p1 = __shfl_xor((int)u1, 1);
  int p2 = __shfl_xor((int)u2, 1);
  int p3 = __shfl_xor((int)u3, 1);
  if (!(lj & 1)) {
    unsigned* q0 = (unsigned*)(base + (size_t)(bq + 0) * H_ + j0 + lj);
    unsigned* q1 = (unsigned*)(base + (size_t)(bq + 1) * H_ + j0 + lj);
    unsigned* q2 = (unsigned*)(base + (size_t)(bq + 2) * H_ + j0 + lj);
    unsigned* q3 = (unsigned*)(base + (size_t)(bq + 3) * H_ + j0 + lj);
    __hip_atomic_store(q0, (unsigned)u0 | ((unsigned)p0 << 16), __ATOMIC_RELAXED, __HIP_MEMORY_SCOPE_AGENT);
    __hip_atomic_store(q1, (unsigned)u1 | ((unsigned)p1 << 16), __ATOMIC_RELAXED, __HIP_MEMORY_SCOPE_AGENT);
    __hip_atomic_store(q2, (unsigned)u2 | ((unsigned)p2 << 16), __ATOMIC_RELAXED, __HIP_MEMORY_SCOPE_AGENT);
    __hip_atomic_store(q3, (unsigned)u3 | ((unsigned)p3 << 16), __ATOMIC_RELAXED, __HIP_MEMORY_SCOPE_AGENT);
  }
}

// ---------------- persistent MFMA GRU scan ----------------
// 32 blocks x 256 threads (4 waves). Wave = (tile, khalf): tile in {0,1} of this
// block's 2 feature-tiles (16 features each), khalf splits K=1024 in two.
// Weights live in registers as MFMA B-fragments (f16). D[batch][feature] via
// mfma_f32_16x16x32_f16; K-halves combined through LDS. All cross-block traffic
// is relaxed agent-scope (LLC-coherent, no invalidates).
__global__ __launch_bounds__(256, 1) void k_scan(
    const float* __restrict__ Gx,   // [S][B][3H] f32 (z|r|n)
    const float* __restrict__ Whz, const float* __restrict__ Whr, const float* __restrict__ Whn,
    unsigned short* __restrict__ Hseq,  // [S][B][H] f16: comm medium + GEMM input
    unsigned short* __restrict__ rhc,   // [B][H] f16: r*h comm
    float* __restrict__ hfin,           // [B][H] f32 (d_out tail)
    unsigned* __restrict__ flags) {
  const int tid = threadIdx.x, lane = tid & 63, wave = tid >> 6;
  const int tile = wave >> 1, kh = wave & 1;
  const bool leader = (kh == 0);
  const int j0 = (blockIdx.x * 2 + tile) * 16;
  const int lj = lane & 15, lq = lane >> 4;   // col-in-tile / quad
  const int kb = kh * 512;
  const int bq = lq * 4;

  __shared__ __align__(16) float comb[2][2][64][4];

  // ---- preload weights as B-fragments: lane holds W[j0+lj][kb+kk*32+lq*8 ..+8] ----
  short8 wz[16], wr[16], wn[16];
  {
    const size_t row = (size_t)(j0 + lj) * H_;
#pragma unroll
    for (int kk = 0; kk < 16; ++kk) {
      int col = kb + kk * 32 + lq * 8;
      const float* pz = Whz + row + col;
      const float* pr = Whr + row + col;
      const float* pn = Whn + row + col;
      short8 a, b, c;
#pragma unroll
      for (int e = 0; e < 8; ++e) {
        a[e] = (short)f2h(pz[e]);
        b[e] = (short)f2h(pr[e]);
        c[e] = (short)f2h(pn[e]);
      }
      wz[kk] = a; wr[kk] = b; wn[kk] = c;
    }
  }

  float hold[4] = {0.f, 0.f, 0.f, 0.f};
  float zv[4] = {0.f, 0.f, 0.f, 0.f};
  const f32x4 zero4 = {0.f, 0.f, 0.f, 0.f};
  unsigned* myflag = flags + (unsigned)blockIdx.x * 32u;

  for (int t = 0; t < S_; ++t) {
    const float* gxt = Gx + (size_t)t * (B_ * 3 * H_);
    // gx prefetch (normal cached loads; no flag dependency)
    float gz[4], gr[4], gn[4];
    if (leader) {
#pragma unroll
      for (int r = 0; r < 4; ++r) {
        const float* gb = gxt + (size_t)(bq + r) * (3 * H_) + j0 + lj;
        gz[r] = gb[0]; gr[r] = gb[H_]; gn[r] = gb[2 * H_];
      }
    }

    // ---------- phase A: z, r ----------
    f32x4 zacc = zero4, racc = zero4;
    if (t > 0) {
      pollf(flags, (unsigned)(2 * t - 1));
      const unsigned short* hsrc = Hseq + (size_t)(t - 1) * (B_ * H_);
      F8 a[16];
#pragma unroll
      for (int kk = 0; kk < 16; ++kk) {  // A-frag: batch = lj (lane&15), k-chunk by lq
        ull* p = (ull*)(hsrc + (size_t)lj * H_ + kb + kk * 32 + lq * 8);
        a[kk].u[0] = __hip_atomic_load(p, __ATOMIC_RELAXED, __HIP_MEMORY_SCOPE_AGENT);
        a[kk].u[1] = __hip_atomic_load(p + 1, __ATOMIC_RELAXED, __HIP_MEMORY_SCOPE_AGENT);
      }
#pragma unroll
      for (int kk = 0; kk < 16; ++kk) {
        zacc = __builtin_amdgcn_mfma_f32_16x16x32_f16(a[kk].s8, wz[kk], zacc, 0, 0, 0);
        racc = __builtin_amdgcn_mfma_f32_16x16x32_f16(a[kk].s8, wr[kk], racc, 0, 0, 0);
      }
      if (!leader) {
        *(f32x4*)&comb[tile][0][lane][0] = zacc;
        *(f32x4*)&comb[tile][1][lane][0] = racc;
      }
      __syncthreads();
      if (leader) {
        zacc += *(const f32x4*)&comb[tile][0][lane][0];
        racc += *(const f32x4*)&comb[tile][1][lane][0];
      }
    }
    unsigned short u0 = 0, u1 = 0, u2 = 0, u3 = 0;
    if (leader) {
      float rhv[4];
#pragma unroll
      for (int r = 0; r < 4; ++r) {
        zv[r] = 1.f / (1.f + __expf(-(gz[r] + zacc[r])));
        float rv = 1.f / (1.f + __expf(-(gr[r] + racc[r])));
        rhv[r] = rv * hold[r];
      }
      u0 = f2h(rhv[0]); u1 = f2h(rhv[1]); u2 = f2h(rhv[2]); u3 = f2h(rhv[3]);
    }
    if (t > 0) {   // t==0: rh==0 globally, phase B skips its matmul
      if (leader) pack_store(rhc, j0, lj, bq, u0, u1, u2, u3);
      asm volatile("s_waitcnt vmcnt(0)" ::: "memory");
      __syncthreads();
      if (tid == 0)
        __hip_atomic_store(myflag, (unsigned)(2 * t), __ATOMIC_RELAXED, __HIP_MEMORY_SCOPE_AGENT);
    }

    // ---------- phase B: n, h update ----------
    f32x4 nacc = zero4;
    if (t > 0) {
      pollf(flags, (unsigned)(2 * t));
      F8 a[16];
#pragma unroll
      for (int kk = 0; kk < 16; ++kk) {
        ull* p = (ull*)(rhc + (size_t)lj * H_ + kb + kk * 32 + lq * 8);
        a[kk].u[0] = __hip_atomic_load(p, __ATOMIC_RELAXED, __HIP_MEMORY_SCOPE_AGENT);
        a[kk].u[1] = __hip_atomic_load(p + 1, __ATOMIC_RELAXED, __HIP_MEMORY_SCOPE_AGENT);
      }
#pragma unroll
      for (int kk = 0; kk < 16; ++kk)
        nacc = __builtin_amdgcn_mfma_f32_16x16x32_f16(a[kk].s8, wn[kk], nacc, 0, 0, 0);
      if (!leader) *(f32x4*)&comb[tile][0][lane][0] = nacc;
      __syncthreads();
      if (leader) nacc += *(const f32x4*)&comb[tile][0][lane][0];
    }
    if (leader) {
      float hn[4];
#pragma unroll
      for (int r = 0; r < 4; ++r) {
        float nv = tanhf(gn[r] + nacc[r]);
        hn[r] = (1.f - zv[r]) * nv + zv[r] * hold[r];
        hold[r] = hn[r];
        if (t == S_ - 1) hfin[(size_t)(bq + r) * H_ + j0 + lj] = hn[r];
      }
      pack_store(Hseq + (size_t)t * (B_ * H_), j0, lj, bq,
                 f2h(hn[0]), f2h(hn[1]), f2h(hn[2]), f2h(hn[3]));
    }
    asm volatile("s_waitcnt vmcnt(0)" ::: "memory");
    __syncthreads();
    if (tid == 0)
      __hip_atomic_store(myflag, (unsigned)(2 * t + 1), __ATOMIC_RELAXED, __HIP_MEMORY_SCOPE_AGENT);
  }
}

// ---------------- host ----------------

extern "C" void kernel_launch(void* const* d_in, const int* in_sizes, int n_in,
                              void* d_out, int out_size, void* d_ws, size_t ws_size,
                              hipStream_t stream) {
  const int*   x    = (const int*)d_in[0];
  const float* emb  = (const float*)d_in[1];
  const float* wxz0 = (const float*)d_in[2];
  const float* bxz0 = (const float*)d_in[3];
  const float* whz0 = (const float*)d_in[4];
  const float* wxr0 = (const float*)d_in[5];
  const float* bxr0 = (const float*)d_in[6];
  const float* whr0 = (const float*)d_in[7];
  const float* wxn0 = (const float*)d_in[8];
  const float* bxn0 = (const float*)d_in[9];
  const float* whn0 = (const float*)d_in[10];
  const float* wxz1 = (const float*)d_in[11];
  const float* bxz1 = (const float*)d_in[12];
  const float* whz1 = (const float*)d_in[13];
  const float* wxr1 = (const float*)d_in[14];
  const float* bxr1 = (const float*)d_in[15];
  const float* whr1 = (const float*)d_in[16];
  const float* wxn1 = (const float*)d_in[17];
  const float* bxn1 = (const float*)d_in[18];
  const float* whn1 = (const float*)d_in[19];
  const float* fcw  = (const float*)d_in[20];
  const float* fcb  = (const float*)d_in[21];
  float* out = (float*)d_out;

  char* w = (char*)d_ws;
  size_t off = 0;
  auto alloc = [&](size_t bytes) {
    void* p = w + off;
    off += (bytes + 255) & ~(size_t)255;
    return p;
  };
  unsigned short* xe   = (unsigned short*)alloc((size_t)4096 * E_ * 2);
  unsigned short* wz0b = (unsigned short*)alloc((size_t)H_ * E_ * 2);
  unsigned short* wr0b = (unsigned short*)alloc((size_t)H_ * E_ * 2);
  unsigned short* wn0b = (unsigned short*)alloc((size_t)H_ * E_ * 2);
  unsigned short* wz1b = (unsigned short*)alloc((size_t)H_ * H_ * 2);
  unsigned short* wr1b = (unsigned short*)alloc((size_t)H_ * H_ * 2);
  unsigned short* wn1b = (unsigned short*)alloc((size_t)H_ * H_ * 2);
  unsigned short* fcwb = (unsigned short*)alloc((size_t)V_ * H_ * 2);
  float* Gx = (float*)alloc((size_t)4096 * 3 * H_ * 4);
  unsigned short* Hs0 = (unsigned short*)alloc((size_t)4096 * H_ * 2);
  unsigned short* Hs1 = (unsigned short*)alloc((size_t)4096 * H_ * 2);
  unsigned short* rhc = (unsigned short*)alloc((size_t)B_ * H_ * 2);
  unsigned* flags0 = (unsigned*)alloc((size_t)SCAN_NB * 32 * 4);  // 128B-spaced epochs
  unsigned* flags1 = (unsigned*)alloc((size_t)SCAN_NB * 32 * 4);

  float* h0f = out + (size_t)B_ * S_ * V_;
  float* h1f = h0f + (size_t)B_ * H_;

  // zero both flag arrays (contiguous)
  {
    int nz = SCAN_NB * 32 * 2;
    k_init<<<(nz + 255) / 256, 256, 0, stream>>>(flags0, nz);
  }

  // prep: gather + casts (f16)
  k_gather<<<4096, 128, 0, stream>>>(x, emb, xe);
  k_cast<<<(H_ * E_ / 4 + 255) / 256, 256, 0, stream>>>(wxz0, wz0b, H_ * E_ / 4);
  k_cast<<<(H_ * E_ / 4 + 255) / 256, 256, 0, stream>>>(wxr0, wr0b, H_ * E_ / 4);
  k_cast<<<(H_ * E_ / 4 + 255) / 256, 256, 0, stream>>>(wxn0, wn0b, H_ * E_ / 4);
  k_cast<<<(H_ * H_ / 4 + 255) / 256, 256, 0, stream>>>(wxz1, wz1b, H_ * H_ / 4);
  k_cast<<<(H_ * H_ / 4 + 255) / 256, 256, 0, stream>>>(wxr1, wr1b, H_ * H_ / 4);
  k_cast<<<(H_ * H_ / 4 + 255) / 256, 256, 0, stream>>>(wxn1, wn1b, H_ * H_ / 4);
  k_cast<<<(V_ * H_ / 4 + 255) / 256, 256, 0, stream>>>(fcw, fcwb, V_ * H_ / 4);

  // Gx0 = xe @ Wx0^T + b  (M=4096, N=3072, K=512)
  k_gemm<<<32 * 24, 256, 0, stream>>>(xe, wz0b, wr0b, wn0b, bxz0, bxr0, bxn0,
                                      Gx, E_, 32, 10, 0, 3 * H_);
  // layer-0 scan
  k_scan<<<SCAN_NB, 256, 0, stream>>>(Gx, whz0, whr0, whn0, Hs0, rhc, h0f, flags0);
  // Gx1 = Hs0 @ Wx1^T + b  (K=1024)
  k_gemm<<<32 * 24, 256, 0, stream>>>(Hs0, wz1b, wr1b, wn1b, bxz1, bxr1, bxn1,
                                      Gx, H_, 32, 10, 0, 3 * H_);
  // layer-1 scan
  k_scan<<<SCAN_NB, 256, 0, stream>>>(Gx, whz1, whr1, whn1, Hs1, rhc, h1f, flags1);
  // out = Hs1 @ fcw^T + fcb  (M=4096, N=32000, K=1024), permuted to [B][S][V]
  k_gemm<<<32 * 250, 256, 0, stream>>>(Hs1, fcwb, fcwb, fcwb, fcb, fcb, fcb,
                                       out, H_, 32, 30, 1, V_);

  (void)in_sizes; (void)n_in; (void)out_size; (void)ws_size;
}